// Round 8
// baseline (195.824 us; speedup 1.0000x reference)
//
#include <hip/hip_runtime.h>

typedef _Float16 half8 __attribute__((ext_vector_type(8)));
typedef __fp16  fp16x2 __attribute__((ext_vector_type(2)));
typedef float f32x4 __attribute__((ext_vector_type(4)));

#define HH 6144
#define WW 6144
#define KH 11
#define KW 11
#define OH (HH - KH + 1)   // 6134
#define OW (WW - KW + 1)   // 6134

#define BROWS 64           // out rows per block (wave w owns rows 16w..16w+15)
#define BCOLS 128          // out cols per block (8 col-tiles of 16)
#define SROWS 74           // staged input rows
#define SCOLS 144          // staged input cols (need 143)
#define RS 164             // LDS row stride in halves (328 B; ~2-way bank alias = free)

#define NTASK (SROWS * (SCOLS / 4))   // 2664 float4 stage tasks

#define TILES_X 48
#define TILES_Y 96
#define NWG (TILES_X * TILES_Y)       // 4608

// ---- prep: B fragments in exact lane order -------------------------------
// Bp[(kb*64 + l)*8 + e] = W[kb][q-n], q=(l>>4)*8+e, n=l&15
__global__ void build_B_kernel(const float* __restrict__ Wt,
                               _Float16* __restrict__ Bp) {
    const int t = (int)blockIdx.x * 256 + (int)threadIdx.x;
    if (t < 11 * 64 * 8) {
        const int e  = t & 7;
        const int l  = (t >> 3) & 63;
        const int kb = t >> 9;          // = ki
        const int n  = l & 15;
        const int q  = (l >> 4) * 8 + e;
        const int d  = q - n;
        float v = (d >= 0 && d < KW) ? Wt[kb * KW + d] : 0.f;
        Bp[t] = (_Float16)v;
    }
}

union pk2 { fp16x2 h; unsigned int u; };
static __device__ inline unsigned int cvt2(float a, float b) {
#if defined(__has_builtin) && __has_builtin(__builtin_amdgcn_cvt_pkrtz)
    pk2 r; r.h = __builtin_amdgcn_cvt_pkrtz(a, b);
#else
    pk2 r; r.h[0] = (__fp16)a; r.h[1] = (__fp16)b;
#endif
    return r.u;
}

__global__ __launch_bounds__(256, 4)
void conv2d_mfma3_kernel(const float* __restrict__ X,
                         const _Float16* __restrict__ Bp,
                         const float* __restrict__ bias,
                         float* __restrict__ out)
{
    __shared__ _Float16 lds[SROWS * RS];    // 24272 B, row-major

    const int bid = (int)blockIdx.x;
    const int xcd = bid & 7;
    const int loc = bid >> 3;
    const int txt = xcd * 6 + loc / TILES_Y;
    const int tyt = loc % TILES_Y;

    const int x0 = txt * BCOLS;
    const int y0 = tyt * BROWS;
    const int tid = (int)threadIdx.x;
    const int lane = tid & 63;
    const int n = lane & 15;
    const int h = lane >> 4;
    const int w = tid >> 6;

    const float bv = bias[0];
    const bool interiorS = (x0 + SCOLS <= WW) && (y0 + SROWS <= HH);

    half8 Bf[11];

    if (interiorS) {
        // ---- phase 1: issue ALL stage loads (11 independent float4/thread) --
        float4 L[11];
        #pragma unroll
        for (int it = 0; it < 11; ++it) {
            const int idx = it * 256 + tid;
            if (idx < NTASK) {
                const int row = idx / 36;
                const int j   = idx - row * 36;
                L[it] = *reinterpret_cast<const float4*>(
                    &X[(size_t)(y0 + row) * WW + (x0 + 4 * j)]);
            }
        }
        // ---- weight fragments (L2-hot) hide under the stage loads ----------
        const _Float16* bp = Bp + (size_t)lane * 8;
        #pragma unroll
        for (int kb = 0; kb < 11; ++kb) {
            Bf[kb] = *reinterpret_cast<const half8*>(bp + kb * 64 * 8);
            asm volatile("" : "+v"(Bf[kb]));   // pin: forbid sinking/remat
        }
        // ---- phase 2: convert + LDS write -----------------------------------
        #pragma unroll
        for (int it = 0; it < 11; ++it) {
            const int idx = it * 256 + tid;
            if (idx < NTASK) {
                const int row = idx / 36;
                const int j   = idx - row * 36;
                uint2 pk;
                pk.x = cvt2(L[it].x, L[it].y);
                pk.y = cvt2(L[it].z, L[it].w);
                *reinterpret_cast<uint2*>(&lds[row * RS + 4 * j]) = pk;
            }
        }
    } else {
        const _Float16* bp = Bp + (size_t)lane * 8;
        #pragma unroll
        for (int kb = 0; kb < 11; ++kb) {
            Bf[kb] = *reinterpret_cast<const half8*>(bp + kb * 64 * 8);
            asm volatile("" : "+v"(Bf[kb]));
        }
        #pragma unroll
        for (int it = 0; it < 11; ++it) {
            const int idx = it * 256 + tid;
            if (idx < NTASK) {
                const int row = idx / 36;
                const int j   = idx - row * 36;
                const int gy  = y0 + row;
                const int gx  = x0 + 4 * j;
                float v0 = 0.f, v1 = 0.f, v2 = 0.f, v3 = 0.f;
                if (gy < HH) {
                    const float* rp = X + (size_t)gy * WW;
                    if (gx + 0 < WW) v0 = rp[gx + 0];
                    if (gx + 1 < WW) v1 = rp[gx + 1];
                    if (gx + 2 < WW) v2 = rp[gx + 2];
                    if (gx + 3 < WW) v3 = rp[gx + 3];
                }
                uint2 pk;
                pk.x = cvt2(v0, v1);
                pk.y = cvt2(v2, v3);
                *reinterpret_cast<uint2*>(&lds[row * RS + 4 * j]) = pk;
            }
        }
    }

    f32x4 acc[8];
    #pragma unroll
    for (int t = 0; t < 8; ++t) acc[t] = (f32x4){bv, bv, bv, bv};

    __syncthreads();

    // ---- compute: A-frag = one b128 (base + const offset), zero inner VALU -
    const char* ab = reinterpret_cast<const char*>(lds)
                   + ((16 * w + n) * RS + 8 * h) * 2;
    #pragma unroll
    for (int kb = 0; kb < 11; ++kb) {
        #pragma unroll
        for (int t = 0; t < 8; ++t) {
            half8 a = *reinterpret_cast<const half8*>(ab + kb * (RS * 2) + t * 32);
            acc[t] = __builtin_amdgcn_mfma_f32_16x16x32_f16(a, Bf[kb], acc[t], 0, 0, 0);
        }
    }

    // ---- store: out row 16w+4h+r, col 16t+n --------------------------------
    const int gy0 = y0 + 16 * w + 4 * h;
    const int gx0 = x0 + n;
    const bool interiorD = (x0 + BCOLS <= OW) && (y0 + BROWS <= OH);
    if (interiorD) {
        #pragma unroll
        for (int r = 0; r < 4; ++r) {
            float* op = out + (size_t)(gy0 + r) * OW + gx0;
            #pragma unroll
            for (int t = 0; t < 8; ++t)
                op[t * 16] = acc[t][r];
        }
    } else {
        #pragma unroll
        for (int r = 0; r < 4; ++r) {
            const int oy = gy0 + r;
            if (oy < OH) {
                float* op = out + (size_t)oy * OW + gx0;
                #pragma unroll
                for (int t = 0; t < 8; ++t)
                    if (gx0 + t * 16 < OW) op[t * 16] = acc[t][r];
            }
        }
    }
}

extern "C" void kernel_launch(void* const* d_in, const int* in_sizes, int n_in,
                              void* d_out, int out_size, void* d_ws, size_t ws_size,
                              hipStream_t stream) {
    const float* X    = (const float*)d_in[0];
    const float* Wt   = (const float*)d_in[1];
    const float* bias = (const float*)d_in[2];
    float* out        = (float*)d_out;
    _Float16* Bp      = (_Float16*)d_ws;      // 11264 B

    build_B_kernel<<<dim3(22), dim3(256), 0, stream>>>(Wt, Bp);
    conv2d_mfma3_kernel<<<dim3(NWG), dim3(256), 0, stream>>>(X, Bp, bias, out);
}

// Round 9
// 195.392 us; speedup vs baseline: 1.0022x; 1.0022x over previous
//
#include <hip/hip_runtime.h>

typedef _Float16 half8 __attribute__((ext_vector_type(8)));
typedef __fp16  fp16x2 __attribute__((ext_vector_type(2)));
typedef float f32x4 __attribute__((ext_vector_type(4)));

#define HH 6144
#define WW 6144
#define KH 11
#define KW 11
#define OH (HH - KH + 1)   // 6134
#define OW (WW - KW + 1)   // 6134

#define BROWS 64           // out rows per block (wave w owns rows 16w..16w+15)
#define BCOLS 128          // out cols per block (8 col-tiles of 16)
#define SROWS 74           // staged input rows
#define SCOLS 144          // staged input cols (need 143)
#define RS 164             // LDS row stride in halves (328 B; ~2-way bank alias = free)

#define NTASK (SROWS * (SCOLS / 4))   // 2664 float4 stage tasks; it<10 unguarded

#define TILES_X 48
#define TILES_Y 96
#define NWG (TILES_X * TILES_Y)       // 4608

// ---- prep: B fragments in exact lane order -------------------------------
// Bp[(kb*64 + l)*8 + e] = W[kb][q-n], q=(l>>4)*8+e, n=l&15
__global__ void build_B_kernel(const float* __restrict__ Wt,
                               _Float16* __restrict__ Bp) {
    const int t = (int)blockIdx.x * 256 + (int)threadIdx.x;
    if (t < 11 * 64 * 8) {
        const int e  = t & 7;
        const int l  = (t >> 3) & 63;
        const int kb = t >> 9;          // = ki
        const int n  = l & 15;
        const int q  = (l >> 4) * 8 + e;
        const int d  = q - n;
        float v = (d >= 0 && d < KW) ? Wt[kb * KW + d] : 0.f;
        Bp[t] = (_Float16)v;
    }
}

union pk2 { fp16x2 h; unsigned int u; };
static __device__ inline unsigned int cvt2(float a, float b) {
#if defined(__has_builtin) && __has_builtin(__builtin_amdgcn_cvt_pkrtz)
    pk2 r; r.h = __builtin_amdgcn_cvt_pkrtz(a, b);
#else
    pk2 r; r.h[0] = (__fp16)a; r.h[1] = (__fp16)b;
#endif
    return r.u;
}

// Inline-asm load: issue order is program order; compiler can't insert waitcnt
// between these (it doesn't model them), so all 11 stay in flight.
#define GLOAD4(dst, ptr) \
    asm volatile("global_load_dwordx4 %0, %1, off" : "=v"(dst) : "v"(ptr))

__global__ __launch_bounds__(256, 4)
void conv2d_mfma4_kernel(const float* __restrict__ X,
                         const _Float16* __restrict__ Bp,
                         const float* __restrict__ bias,
                         float* __restrict__ out)
{
    __shared__ _Float16 lds[SROWS * RS];    // 24272 B, row-major

    const int bid = (int)blockIdx.x;
    const int xcd = bid & 7;
    const int loc = bid >> 3;
    const int txt = xcd * 6 + loc / TILES_Y;
    const int tyt = loc % TILES_Y;

    const int x0 = txt * BCOLS;
    const int y0 = tyt * BROWS;
    const int tid = (int)threadIdx.x;
    const int lane = tid & 63;
    const int n = lane & 15;
    const int h = lane >> 4;
    const int w = tid >> 6;

    const float bv = bias[0];
    const bool interiorS = (x0 + SCOLS <= WW) && (y0 + SROWS <= HH);

    half8 Bf[11];
    const _Float16* bp = Bp + (size_t)lane * 8;

    if (interiorS) {
        // ---- phase 1: issue ALL 11 stage loads back-to-back (asm) ----------
        float4 L[11];
        #pragma unroll
        for (int it = 0; it < 11; ++it) {
            const int idx = it * 256 + tid;
            if (it < 10 || idx < NTASK) {
                const int row = idx / 36;
                const int j   = idx - row * 36;
                const float* p = &X[(size_t)(y0 + row) * WW + (x0 + 4 * j)];
                GLOAD4(L[it], p);
            }
        }
        // ---- weight fragments (L2-hot) issue behind the stage loads --------
        #pragma unroll
        for (int kb = 0; kb < 11; ++kb) {
            Bf[kb] = *reinterpret_cast<const half8*>(bp + kb * 64 * 8);
            asm volatile("" : "+v"(Bf[kb]));   // pin: forbid sinking into MFMA loop
        }
        // ---- drain, then convert + LDS write -------------------------------
        asm volatile("s_waitcnt vmcnt(0)" ::: "memory");
        __builtin_amdgcn_sched_barrier(0);     // nothing moves above the wait
        #pragma unroll
        for (int it = 0; it < 11; ++it) {
            const int idx = it * 256 + tid;
            if (it < 10 || idx < NTASK) {
                const int row = idx / 36;
                const int j   = idx - row * 36;
                uint2 pk;
                pk.x = cvt2(L[it].x, L[it].y);
                pk.y = cvt2(L[it].z, L[it].w);
                *reinterpret_cast<uint2*>(&lds[row * RS + 4 * j]) = pk;
            }
        }
    } else {
        #pragma unroll
        for (int kb = 0; kb < 11; ++kb) {
            Bf[kb] = *reinterpret_cast<const half8*>(bp + kb * 64 * 8);
            asm volatile("" : "+v"(Bf[kb]));
        }
        #pragma unroll
        for (int it = 0; it < 11; ++it) {
            const int idx = it * 256 + tid;
            if (idx < NTASK) {
                const int row = idx / 36;
                const int j   = idx - row * 36;
                const int gy  = y0 + row;
                const int gx  = x0 + 4 * j;
                float v0 = 0.f, v1 = 0.f, v2 = 0.f, v3 = 0.f;
                if (gy < HH) {
                    const float* rp = X + (size_t)gy * WW;
                    if (gx + 0 < WW) v0 = rp[gx + 0];
                    if (gx + 1 < WW) v1 = rp[gx + 1];
                    if (gx + 2 < WW) v2 = rp[gx + 2];
                    if (gx + 3 < WW) v3 = rp[gx + 3];
                }
                uint2 pk;
                pk.x = cvt2(v0, v1);
                pk.y = cvt2(v2, v3);
                *reinterpret_cast<uint2*>(&lds[row * RS + 4 * j]) = pk;
            }
        }
    }

    f32x4 acc[8];
    #pragma unroll
    for (int t = 0; t < 8; ++t) acc[t] = (f32x4){bv, bv, bv, bv};

    __syncthreads();

    // ---- compute: A-frag = one b128 (base + const offset), zero inner VALU -
    const char* ab = reinterpret_cast<const char*>(lds)
                   + ((16 * w + n) * RS + 8 * h) * 2;
    #pragma unroll
    for (int kb = 0; kb < 11; ++kb) {
        #pragma unroll
        for (int t = 0; t < 8; ++t) {
            half8 a = *reinterpret_cast<const half8*>(ab + kb * (RS * 2) + t * 32);
            acc[t] = __builtin_amdgcn_mfma_f32_16x16x32_f16(a, Bf[kb], acc[t], 0, 0, 0);
        }
    }

    // ---- store: out row 16w+4h+r, col 16t+n --------------------------------
    const int gy0 = y0 + 16 * w + 4 * h;
    const int gx0 = x0 + n;
    const bool interiorD = (x0 + BCOLS <= OW) && (y0 + BROWS <= OH);
    if (interiorD) {
        #pragma unroll
        for (int r = 0; r < 4; ++r) {
            float* op = out + (size_t)(gy0 + r) * OW + gx0;
            #pragma unroll
            for (int t = 0; t < 8; ++t)
                op[t * 16] = acc[t][r];
        }
    } else {
        #pragma unroll
        for (int r = 0; r < 4; ++r) {
            const int oy = gy0 + r;
            if (oy < OH) {
                float* op = out + (size_t)oy * OW + gx0;
                #pragma unroll
                for (int t = 0; t < 8; ++t)
                    if (gx0 + t * 16 < OW) op[t * 16] = acc[t][r];
            }
        }
    }
}

extern "C" void kernel_launch(void* const* d_in, const int* in_sizes, int n_in,
                              void* d_out, int out_size, void* d_ws, size_t ws_size,
                              hipStream_t stream) {
    const float* X    = (const float*)d_in[0];
    const float* Wt   = (const float*)d_in[1];
    const float* bias = (const float*)d_in[2];
    float* out        = (float*)d_out;
    _Float16* Bp      = (_Float16*)d_ws;      // 11264 B

    build_B_kernel<<<dim3(22), dim3(256), 0, stream>>>(Wt, Bp);
    conv2d_mfma4_kernel<<<dim3(NWG), dim3(256), 0, stream>>>(X, Bp, bias, out);
}

// Round 10
// 193.500 us; speedup vs baseline: 1.0120x; 1.0098x over previous
//
#include <hip/hip_runtime.h>

typedef _Float16 half8 __attribute__((ext_vector_type(8)));
typedef __fp16  fp16x2 __attribute__((ext_vector_type(2)));
typedef float f32x4 __attribute__((ext_vector_type(4)));

#define HH 6144
#define WW 6144
#define KH 11
#define KW 11
#define OH (HH - KH + 1)   // 6134
#define OW (WW - KW + 1)   // 6134

#define TX 48              // stripe columns (128 out cols each)
#define TY 48              // stripe rows (128 out rows each)
#define NWG (TX * TY)      // 2304 = 8 XCDs * 288
#define BC 128             // out cols per block
#define SLABS 8
#define SR 16              // out rows per slab
#define SCOLS 144          // staged input cols (need 143)
#define RSH 164            // halves per ring row (328 B; 82 dw = 18 mod 32, ~0 conflicts @ r6)
#define RB 328             // ring row bytes
#define RING 64            // ring rows (&63), 20992 B LDS

// ---- prep: B fragments in exact lane order (verified rounds 6-8) ----------
// Bp[(kb*64 + l)*8 + e] = W[kb][q-n], q=(l>>4)*8+e, n=l&15
__global__ void build_B_kernel(const float* __restrict__ Wt,
                               _Float16* __restrict__ Bp) {
    const int t = (int)blockIdx.x * 256 + (int)threadIdx.x;
    if (t < 11 * 64 * 8) {
        const int e  = t & 7;
        const int l  = (t >> 3) & 63;
        const int kb = t >> 9;
        const int n  = l & 15;
        const int q  = (l >> 4) * 8 + e;
        const int d  = q - n;
        float v = (d >= 0 && d < KW) ? Wt[kb * KW + d] : 0.f;
        Bp[t] = (_Float16)v;
    }
}

union pk2 { fp16x2 h; unsigned int u; };
static __device__ __forceinline__ unsigned int cvt2(float a, float b) {
#if defined(__has_builtin) && __has_builtin(__builtin_amdgcn_cvt_pkrtz)
    pk2 r; r.h = __builtin_amdgcn_cvt_pkrtz(a, b);
#else
    pk2 r; r.h[0] = (__fp16)a; r.h[1] = (__fp16)b;
#endif
    return r.u;
}

template <bool G>
static __device__ __forceinline__
void stage_direct(const float* __restrict__ X, char* ldsb,
                  int g, int x0, int j) {
    const int gx = x0 + 4 * j;
    float4 v = {0.f, 0.f, 0.f, 0.f};
    if (!G || (g < HH && gx + 3 < WW))
        v = *reinterpret_cast<const float4*>(&X[(size_t)g * WW + gx]);
    uint2 pk;
    pk.x = cvt2(v.x, v.y);
    pk.y = cvt2(v.z, v.w);
    *reinterpret_cast<uint2*>(ldsb + (size_t)(g & 63) * RB + 8 * j) = pk;
}

template <bool G>
static __device__ __forceinline__
void body(const float* __restrict__ X, const _Float16* __restrict__ Bp,
          const float bv, float* __restrict__ out, char* ldsb,
          const int x0, const int y0, const int tid)
{
    const int lane = tid & 63;
    const int n  = lane & 15;
    const int h  = lane >> 4;
    const int wv = tid >> 6;

    // ---- weight fragments once per block (L2-hot); pin after load ----------
    half8 Bf[11];
    const _Float16* bp = Bp + lane * 8;
    #pragma unroll
    for (int kb = 0; kb < 11; ++kb) {
        Bf[kb] = *reinterpret_cast<const half8*>(bp + kb * 512);
        asm volatile("" : "+v"(Bf[kb]));
    }

    // ---- per-thread stage task coords (loop-invariant, computed once) ------
    const int r0 = tid / 36,          j0 = tid - r0 * 36;
    const int t1 = tid + 256;
    const int r1 = t1 / 36,           j1 = t1 - r1 * 36;
    const int t2 = tid + 512;
    const int r2 = t2 / 36,           j2 = t2 - r2 * 36;   // valid iff tid<64

    // ---- prologue: stage input rows y0 .. y0+25 ----------------------------
    #pragma unroll
    for (int it = 0; it < 4; ++it) {
        const int idx = it * 256 + tid;
        if (idx < 26 * 36) {
            const int r = idx / 36;
            const int j = idx - r * 36;
            stage_direct<G>(X, ldsb, y0 + r, x0, j);
        }
    }
    __syncthreads();

    // ---- slab loop ---------------------------------------------------------
    #pragma unroll 1
    for (int s = 0; s < SLABS; ++s) {
        // issue next slab's loads (rows y0+16s+26 .. +41) — hidden under MFMA
        float4 L0 = {0,0,0,0}, L1 = {0,0,0,0}, L2 = {0,0,0,0};
        const int gpre = y0 + 16 * s + 26;
        if (s < SLABS - 1) {
            if (!G) {
                L0 = *reinterpret_cast<const float4*>(&X[(size_t)(gpre + r0) * WW + x0 + 4 * j0]);
                L1 = *reinterpret_cast<const float4*>(&X[(size_t)(gpre + r1) * WW + x0 + 4 * j1]);
                if (tid < 64)
                    L2 = *reinterpret_cast<const float4*>(&X[(size_t)(gpre + r2) * WW + x0 + 4 * j2]);
            } else {
                if (gpre + r0 < HH && x0 + 4 * j0 + 3 < WW)
                    L0 = *reinterpret_cast<const float4*>(&X[(size_t)(gpre + r0) * WW + x0 + 4 * j0]);
                if (gpre + r1 < HH && x0 + 4 * j1 + 3 < WW)
                    L1 = *reinterpret_cast<const float4*>(&X[(size_t)(gpre + r1) * WW + x0 + 4 * j1]);
                if (tid < 64 && gpre + r2 < HH && x0 + 4 * j2 + 3 < WW)
                    L2 = *reinterpret_cast<const float4*>(&X[(size_t)(gpre + r2) * WW + x0 + 4 * j2]);
            }
        }
        __builtin_amdgcn_sched_barrier(0);   // loads stay issued above compute

        // compute slab s: rows y0+16s .. +25 from ring, verified r6 mapping
        f32x4 acc0 = {bv, bv, bv, bv};
        f32x4 acc1 = {bv, bv, bv, bv};
        const int rowb = y0 + 16 * s + n;
        #pragma unroll
        for (int kb = 0; kb < 11; ++kb) {
            const char* pa = ldsb + (size_t)((rowb + kb) & 63) * RB + h * 16 + wv * 64;
            half8 a0 = *reinterpret_cast<const half8*>(pa);
            half8 a1 = *reinterpret_cast<const half8*>(pa + 32);
            acc0 = __builtin_amdgcn_mfma_f32_16x16x32_f16(a0, Bf[kb], acc0, 0, 0, 0);
            acc1 = __builtin_amdgcn_mfma_f32_16x16x32_f16(a1, Bf[kb], acc1, 0, 0, 0);
        }

        // store slab s: out row y0+16s+4h+r, cols x0+32wv+{n, n+16}
        const int orow = y0 + 16 * s + 4 * h;
        const int ocol = x0 + 32 * wv + n;
        #pragma unroll
        for (int r = 0; r < 4; ++r) {
            if (!G) {
                float* op = out + (size_t)(orow + r) * OW + ocol;
                op[0]  = acc0[r];
                op[16] = acc1[r];
            } else if (orow + r < OH) {
                float* op = out + (size_t)(orow + r) * OW + ocol;
                if (ocol      < OW) op[0]  = acc0[r];
                if (ocol + 16 < OW) op[16] = acc1[r];
            }
        }

        __builtin_amdgcn_sched_barrier(0);   // cvt/waitcnt may not hoist above MFMA
        if (s < SLABS - 1) {
            // ring slots (16s+26..41)&63 are disjoint from this slab's read set
            { uint2 pk; pk.x = cvt2(L0.x, L0.y); pk.y = cvt2(L0.z, L0.w);
              *reinterpret_cast<uint2*>(ldsb + (size_t)((gpre + r0) & 63) * RB + 8 * j0) = pk; }
            { uint2 pk; pk.x = cvt2(L1.x, L1.y); pk.y = cvt2(L1.z, L1.w);
              *reinterpret_cast<uint2*>(ldsb + (size_t)((gpre + r1) & 63) * RB + 8 * j1) = pk; }
            if (tid < 64)
            { uint2 pk; pk.x = cvt2(L2.x, L2.y); pk.y = cvt2(L2.z, L2.w);
              *reinterpret_cast<uint2*>(ldsb + (size_t)((gpre + r2) & 63) * RB + 8 * j2) = pk; }
        }
        __syncthreads();
    }
}

__global__ __launch_bounds__(256, 4)
void conv2d_ring_kernel(const float* __restrict__ X,
                        const _Float16* __restrict__ Bp,
                        const float* __restrict__ bias,
                        float* __restrict__ out)
{
    __shared__ _Float16 lds[RING * RSH];    // 20992 B

    // XCD-chunked remap: XCD k gets 288 consecutive tiles (6 full row-bands)
    const int bid = (int)blockIdx.x;
    const int sb  = (bid & 7) * (NWG / 8) + (bid >> 3);
    const int txt = sb % TX;
    const int tyt = sb / TX;

    const int x0 = txt * BC;
    const int y0 = tyt * (SLABS * SR);
    const int tid = (int)threadIdx.x;
    const float bv = bias[0];
    char* ldsb = reinterpret_cast<char*>(lds);

    if (txt < TX - 1 && tyt < TY - 1)
        body<false>(X, Bp, bv, out, ldsb, x0, y0, tid);
    else
        body<true>(X, Bp, bv, out, ldsb, x0, y0, tid);
}

extern "C" void kernel_launch(void* const* d_in, const int* in_sizes, int n_in,
                              void* d_out, int out_size, void* d_ws, size_t ws_size,
                              hipStream_t stream) {
    const float* X    = (const float*)d_in[0];
    const float* Wt   = (const float*)d_in[1];
    const float* bias = (const float*)d_in[2];
    float* out        = (float*)d_out;
    _Float16* Bp      = (_Float16*)d_ws;      // 11264 B

    build_B_kernel<<<dim3(22), dim3(256), 0, stream>>>(Wt, Bp);
    conv2d_ring_kernel<<<dim3(NWG), dim3(256), 0, stream>>>(X, Bp, bias, out);
}

// Round 11
// 86.706 us; speedup vs baseline: 2.2585x; 2.2317x over previous
//
#include <hip/hip_runtime.h>

typedef _Float16 half8 __attribute__((ext_vector_type(8)));
typedef __fp16  fp16x2 __attribute__((ext_vector_type(2)));
typedef float f32x4 __attribute__((ext_vector_type(4)));

#define HH 6144
#define WW 6144
#define KH 11
#define KW 11
#define OH (HH - KH + 1)   // 6134
#define OW (WW - KW + 1)   // 6134

#define BROWS 32           // out rows per block
#define BCOLS 128          // out cols per block
#define SR 42              // staged input rows (32 + 10 halo)
#define SCH 40             // 16B chunks per row (160 f32 staged; need 143; 40 => swizzle-safe)
#define ROWB 640           // LDS bytes per row (160 dw = 0 mod 32: swizzle supplies the spread)
#define A_TASKS 1680       // 42*40
#define A_PAD 1728         // 27 full waves
#define B_TASKS 704        // 11264/16
#define TOT_WAVETASKS 38   // 27 A + 11 B
#define B_OFF 27648        // A_PAD*16
#define LDSB 38912         // (A_PAD + B_TASKS)*16

#define TILES_X 48
#define TILES_Y 192
#define NWG (TILES_X * TILES_Y)   // 9216 = 8 * 1152

// ---- prep: B fragments in exact lane order (verified rounds 6-9) ----------
// Bp[(kb*64 + l)*8 + e] = W[kb][q-n], q=(l>>4)*8+e, n=l&15
__global__ void build_B_kernel(const float* __restrict__ Wt,
                               _Float16* __restrict__ Bp) {
    const int t = (int)blockIdx.x * 256 + (int)threadIdx.x;
    if (t < 11 * 64 * 8) {
        const int e  = t & 7;
        const int l  = (t >> 3) & 63;
        const int kb = t >> 9;
        const int n  = l & 15;
        const int q  = (l >> 4) * 8 + e;
        const int d  = q - n;
        float v = (d >= 0 && d < KW) ? Wt[kb * KW + d] : 0.f;
        Bp[t] = (_Float16)v;
    }
}

union pk2 { fp16x2 h; unsigned int u; };
static __device__ __forceinline__ unsigned int cvt2(float a, float b) {
#if defined(__has_builtin) && __has_builtin(__builtin_amdgcn_cvt_pkrtz)
    pk2 r; r.h = __builtin_amdgcn_cvt_pkrtz(a, b);
#else
    pk2 r; r.h[0] = (__fp16)a; r.h[1] = (__fp16)b;
#endif
    return r.u;
}

__global__ __launch_bounds__(256, 4)
void conv2d_dma_kernel(const float* __restrict__ X,
                       const _Float16* __restrict__ Bp,
                       const float* __restrict__ bias,
                       float* __restrict__ out)
{
    __shared__ __align__(16) char lds[LDSB];

    // XCD-chunked remap (bijective: 9216 % 8 == 0)
    const int bid = (int)blockIdx.x;
    const int sb  = (bid & 7) * (NWG / 8) + (bid >> 3);
    const int txt = sb % TILES_X;
    const int tyt = sb / TILES_X;

    const int x0 = txt * BCOLS;
    const int y0 = tyt * BROWS;
    const int tid = (int)threadIdx.x;
    const int lane = tid & 63;
    const int wv = tid >> 6;
    const int n  = lane & 15;
    const int h  = lane >> 4;
    const int rt = wv & 1;          // row-tile (0,1)
    const int cs = wv >> 1;         // col strip of 64 (0,1)
    const float bv = bias[0];

    const bool interior = (txt < TILES_X - 1) && (tyt < TILES_Y - 1);

    // ---------------- stage: DMA global -> LDS (no VGPR destinations) -------
    // LDS slot t*16 holds: A task t<A_PAD: X row r=t/40, global chunk (j^(r&7));
    //                      B task: Bp chunk (t - A_PAD).
    if (interior) {
        #pragma unroll
        for (int k = 0; k < 10; ++k) {
            const int wabs = k * 4 + wv;              // wave-uniform
            if (wabs < TOT_WAVETASKS) {
                char* ldst = lds + wabs * 1024;       // uniform base; HW adds lane*16
                const void* src;
                if (wabs < 27) {
                    const int t = wabs * 64 + lane;
                    int r = t / SCH;
                    const int j = t - r * SCH;
                    if (r > SR - 1) r = SR - 1;       // pad tasks: benign addr clamp
                    const int jg = j ^ (r & 7);       // source pre-swizzle
                    src = (const void*)(X + (size_t)(y0 + r) * WW + (x0 + 4 * jg));
                } else {
                    const int tb = (wabs - 27) * 64 + lane;
                    src = (const void*)((const char*)Bp + (size_t)tb * 16);
                }
                __builtin_amdgcn_global_load_lds(
                    (const __attribute__((address_space(1))) void*)src,
                    (__attribute__((address_space(3))) void*)ldst,
                    16, 0, 0);
            }
        }
    } else {
        // guarded fallback: same slots, same swizzle, regular loads + ds_write
        #pragma unroll 1
        for (int k = 0; k < 10; ++k) {
            const int wabs = k * 4 + wv;
            if (wabs < TOT_WAVETASKS) {
                const int t = wabs * 64 + lane;
                if (wabs < 27) {
                    int r = t / SCH;
                    const int j = t - r * SCH;
                    if (r > SR - 1) r = SR - 1;
                    const int jg = j ^ (r & 7);
                    const int gy = y0 + r;
                    const int gx = x0 + 4 * jg;
                    f32x4 v = {0.f, 0.f, 0.f, 0.f};
                    if (gy < HH) {
                        const float* rp = X + (size_t)gy * WW;
                        if (gx + 3 < WW) {
                            v = *reinterpret_cast<const f32x4*>(rp + gx);
                        } else {
                            if (gx + 0 < WW) v[0] = rp[gx + 0];
                            if (gx + 1 < WW) v[1] = rp[gx + 1];
                            if (gx + 2 < WW) v[2] = rp[gx + 2];
                        }
                    }
                    *reinterpret_cast<f32x4*>(lds + (size_t)t * 16) = v;
                } else {
                    const int tb = t - A_PAD;
                    *reinterpret_cast<uint4*>(lds + (size_t)t * 16) =
                        *reinterpret_cast<const uint4*>((const char*)Bp + (size_t)tb * 16);
                }
            }
        }
    }

    f32x4 acc[4];
    #pragma unroll
    for (int c = 0; c < 4; ++c) acc[c] = (f32x4){bv, bv, bv, bv};

    __syncthreads();   // drains all global_load_lds (vmcnt(0)) once per block

    // ---------------- compute: fp32 LDS -> cvt -> MFMA ----------------------
    // A(kb,c) lane(n,h): X row 16rt+n+kb, f32 cols 64cs+16c+8h+[0,8)
    const int arow = 16 * rt + n;
    #pragma unroll
    for (int kb = 0; kb < 11; ++kb) {
        const half8 bf = *reinterpret_cast<const half8*>(
            lds + B_OFF + kb * 1024 + lane * 16);
        const int r = arow + kb;                  // 0..41
        const char* rbase = lds + (size_t)r * ROWB;
        const int s = r & 7;
        #pragma unroll
        for (int c = 0; c < 4; ++c) {
            const int j0 = 16 * cs + 4 * c + 2 * h;     // even chunk index
            f32x4 lo = *reinterpret_cast<const f32x4*>(rbase + ((j0)     ^ s) * 16);
            f32x4 hi = *reinterpret_cast<const f32x4*>(rbase + ((j0 + 1) ^ s) * 16);
            union { unsigned int u[4]; half8 h8; } fr;
            fr.u[0] = cvt2(lo[0], lo[1]);
            fr.u[1] = cvt2(lo[2], lo[3]);
            fr.u[2] = cvt2(hi[0], hi[1]);
            fr.u[3] = cvt2(hi[2], hi[3]);
            acc[c] = __builtin_amdgcn_mfma_f32_16x16x32_f16(fr.h8, bf, acc[c], 0, 0, 0);
        }
    }

    // ---------------- store: out row 16rt+4h+r, col 64cs+16c+n --------------
    const int orow0 = y0 + 16 * rt + 4 * h;
    const int ocol0 = x0 + 64 * cs + n;
    if (interior) {
        #pragma unroll
        for (int r = 0; r < 4; ++r) {
            float* op = out + (size_t)(orow0 + r) * OW + ocol0;
            #pragma unroll
            for (int c = 0; c < 4; ++c)
                op[16 * c] = acc[c][r];
        }
    } else {
        #pragma unroll
        for (int r = 0; r < 4; ++r) {
            if (orow0 + r < OH) {
                float* op = out + (size_t)(orow0 + r) * OW + ocol0;
                #pragma unroll
                for (int c = 0; c < 4; ++c)
                    if (ocol0 + 16 * c < OW) op[16 * c] = acc[c][r];
            }
        }
    }
}

extern "C" void kernel_launch(void* const* d_in, const int* in_sizes, int n_in,
                              void* d_out, int out_size, void* d_ws, size_t ws_size,
                              hipStream_t stream) {
    const float* X    = (const float*)d_in[0];
    const float* Wt   = (const float*)d_in[1];
    const float* bias = (const float*)d_in[2];
    float* out        = (float*)d_out;
    _Float16* Bp      = (_Float16*)d_ws;      // 11264 B

    build_B_kernel<<<dim3(22), dim3(256), 0, stream>>>(Wt, Bp);
    conv2d_dma_kernel<<<dim3(NWG), dim3(256), 0, stream>>>(X, Bp, bias, out);
}

// Round 12
// 76.068 us; speedup vs baseline: 2.5743x; 1.1399x over previous
//
#include <hip/hip_runtime.h>

typedef _Float16 half8 __attribute__((ext_vector_type(8)));
typedef __fp16  fp16x2 __attribute__((ext_vector_type(2)));
typedef float f32x4 __attribute__((ext_vector_type(4)));

#define HH 6144
#define WW 6144
#define KH 11
#define KW 11
#define OH (HH - KH + 1)   // 6134
#define OW (WW - KW + 1)   // 6134

#define BROWS 32           // out rows per block
#define BCOLS 128          // out cols per block
#define SR 42              // staged input rows (32 + 10 halo)
#define SCH 40             // 16B fp32 chunks per row (160 f32; need 143)
#define ROWB 640           // F row bytes (40*16); H row lives inside same span
#define A_TASKS 1680       // 42*40
#define A_PAD 1728         // 27 full DMA waves (pad slots land in [26880,27648))
#define B_TASKS 704        // 11264/16
#define TOT_WAVETASKS 38   // 27 A + 11 B
#define B_OFF 27648        // A_PAD*16
#define LDSB 38912         // B_OFF + 11264
#define CV_TASKS 840       // 42 rows * 20 col-octs

#define TILES_X 48
#define TILES_Y 192
#define NWG (TILES_X * TILES_Y)   // 9216 = 8 * 1152

// ---- prep: B fragments in exact lane order (verified rounds 6-10) ----------
// Bp[(kb*64 + l)*8 + e] = W[kb][q-n], q=(l>>4)*8+e, n=l&15
__global__ void build_B_kernel(const float* __restrict__ Wt,
                               _Float16* __restrict__ Bp) {
    const int t = (int)blockIdx.x * 256 + (int)threadIdx.x;
    if (t < 11 * 64 * 8) {
        const int e  = t & 7;
        const int l  = (t >> 3) & 63;
        const int kb = t >> 9;
        const int n  = l & 15;
        const int q  = (l >> 4) * 8 + e;
        const int d  = q - n;
        float v = (d >= 0 && d < KW) ? Wt[kb * KW + d] : 0.f;
        Bp[t] = (_Float16)v;
    }
}

union pk2 { fp16x2 h; unsigned int u; };
static __device__ __forceinline__ unsigned int cvt2(float a, float b) {
#if defined(__has_builtin) && __has_builtin(__builtin_amdgcn_cvt_pkrtz)
    pk2 r; r.h = __builtin_amdgcn_cvt_pkrtz(a, b);
#else
    pk2 r; r.h[0] = (__fp16)a; r.h[1] = (__fp16)b;
#endif
    return r.u;
}

__global__ __launch_bounds__(256, 4)
void conv2d_dma2_kernel(const float* __restrict__ X,
                        const _Float16* __restrict__ Bp,
                        const float* __restrict__ bias,
                        float* __restrict__ out)
{
    __shared__ __align__(16) char lds[LDSB];

    // XCD-chunked remap (bijective: 9216 % 8 == 0)
    const int bid = (int)blockIdx.x;
    const int sb  = (bid & 7) * (NWG / 8) + (bid >> 3);
    const int txt = sb % TILES_X;
    const int tyt = sb / TILES_X;

    const int x0 = txt * BCOLS;
    const int y0 = tyt * BROWS;
    const int tid = (int)threadIdx.x;
    const int lane = tid & 63;
    const int wv = tid >> 6;
    const int n  = lane & 15;
    const int h  = lane >> 4;
    const int rt = wv & 1;          // row-tile (0,1)
    const int cs = wv >> 1;         // col strip of 64 (0,1)
    const float bv = bias[0];

    const bool interior = (txt < TILES_X - 1) && (tyt < TILES_Y - 1);

    // ---------------- stage: DMA global -> LDS, LINEAR layout ---------------
    // F slot t (t<A_PAD): X row r=t/40 (clamped), chunk j=t%40. B after.
    if (interior) {
        #pragma unroll
        for (int k = 0; k < 10; ++k) {
            const int wabs = k * 4 + wv;              // wave-uniform
            if (wabs < TOT_WAVETASKS) {
                char* ldst = lds + wabs * 1024;       // uniform base; HW adds lane*16
                const void* src;
                if (wabs < 27) {
                    const int t = wabs * 64 + lane;
                    int r = t / SCH;
                    const int j = t - r * SCH;
                    if (r > SR - 1) r = SR - 1;       // pad tasks: benign clamp
                    src = (const void*)(X + (size_t)(y0 + r) * WW + (x0 + 4 * j));
                } else {
                    const int tb = (wabs - 27) * 64 + lane;
                    src = (const void*)((const char*)Bp + (size_t)tb * 16);
                }
                __builtin_amdgcn_global_load_lds(
                    (const __attribute__((address_space(1))) void*)src,
                    (__attribute__((address_space(3))) void*)ldst,
                    16, 0, 0);
            }
        }
    } else {
        #pragma unroll 1
        for (int k = 0; k < 10; ++k) {
            const int wabs = k * 4 + wv;
            if (wabs < TOT_WAVETASKS) {
                const int t = wabs * 64 + lane;
                if (wabs < 27) {
                    int r = t / SCH;
                    const int j = t - r * SCH;
                    if (r > SR - 1) r = SR - 1;
                    const int gy = y0 + r;
                    const int gx = x0 + 4 * j;
                    f32x4 v = {0.f, 0.f, 0.f, 0.f};
                    if (gy < HH) {
                        const float* rp = X + (size_t)gy * WW;
                        if (gx + 3 < WW) {
                            v = *reinterpret_cast<const f32x4*>(rp + gx);
                        } else {
                            if (gx + 0 < WW) v[0] = rp[gx + 0];
                            if (gx + 1 < WW) v[1] = rp[gx + 1];
                            if (gx + 2 < WW) v[2] = rp[gx + 2];
                        }
                    }
                    *reinterpret_cast<f32x4*>(lds + (size_t)t * 16) = v;
                } else {
                    const int tb = t - A_PAD;
                    *reinterpret_cast<uint4*>(lds + (size_t)t * 16) =
                        *reinterpret_cast<const uint4*>((const char*)Bp + (size_t)tb * 16);
                }
            }
        }
    }

    __syncthreads();   // drains all DMA (vmcnt(0)) once

    // ---------------- convert pass: fp32 F -> fp16 H, IN PLACE --------------
    // task idx: r = idx/20, m = idx%20 (col-oct, global cols 8m..8m+7).
    // Phase A: read into regs. Barrier. Phase B: write H row r at
    // r*640 + (r&7)*32 + m*16  (fits: 224+320 <= 640; rotation spreads banks).
    f32x4 CV[4][2];
    #pragma unroll
    for (int it = 0; it < 4; ++it) {
        const int idx = it * 256 + tid;
        if (idx < CV_TASKS) {
            const int r = idx / 20;
            const int m = idx - r * 20;
            const char* frow = lds + (size_t)(r * SCH + 2 * m) * 16;
            CV[it][0] = *reinterpret_cast<const f32x4*>(frow);
            CV[it][1] = *reinterpret_cast<const f32x4*>(frow + 16);
        }
    }

    __syncthreads();   // all F reads complete before any H write

    #pragma unroll
    for (int it = 0; it < 4; ++it) {
        const int idx = it * 256 + tid;
        if (idx < CV_TASKS) {
            const int r = idx / 20;
            const int m = idx - r * 20;
            union { unsigned int u[4]; uint4 q; } fr;
            fr.u[0] = cvt2(CV[it][0][0], CV[it][0][1]);
            fr.u[1] = cvt2(CV[it][0][2], CV[it][0][3]);
            fr.u[2] = cvt2(CV[it][1][0], CV[it][1][1]);
            fr.u[3] = cvt2(CV[it][1][2], CV[it][1][3]);
            *reinterpret_cast<uint4*>(
                lds + (size_t)r * ROWB + (r & 7) * 32 + m * 16) = fr.q;
        }
    }

    f32x4 acc[4];
    #pragma unroll
    for (int c = 0; c < 4; ++c) acc[c] = (f32x4){bv, bv, bv, bv};

    __syncthreads();

    // ---------------- compute: one b128 per MFMA (fp16) ---------------------
    // A(kb,c) lane(n,h): X row r=16rt+n+kb, halves 64cs+16c+8h+[0,8)
    // addr = r*640 + ((n+kb)&7)*32 + 128cs + 32c + 16h
    const char* abase = lds + (16 * rt + n) * ROWB + 128 * cs + 16 * h;
    const char* bbase = lds + B_OFF + lane * 16;
    #pragma unroll
    for (int kb = 0; kb < 11; ++kb) {
        const half8 bf = *reinterpret_cast<const half8*>(bbase + kb * 1024);
        const char* arow = abase + kb * ROWB + ((n + kb) & 7) * 32;
        #pragma unroll
        for (int c = 0; c < 4; ++c) {
            half8 a = *reinterpret_cast<const half8*>(arow + 32 * c);
            acc[c] = __builtin_amdgcn_mfma_f32_16x16x32_f16(a, bf, acc[c], 0, 0, 0);
        }
    }

    // ---------------- store: out row 16rt+4h+r, col 64cs+16c+n --------------
    const int orow0 = y0 + 16 * rt + 4 * h;
    const int ocol0 = x0 + 64 * cs + n;
    if (interior) {
        #pragma unroll
        for (int r = 0; r < 4; ++r) {
            float* op = out + (size_t)(orow0 + r) * OW + ocol0;
            #pragma unroll
            for (int c = 0; c < 4; ++c)
                op[16 * c] = acc[c][r];
        }
    } else {
        #pragma unroll
        for (int r = 0; r < 4; ++r) {
            if (orow0 + r < OH) {
                float* op = out + (size_t)(orow0 + r) * OW + ocol0;
                #pragma unroll
                for (int c = 0; c < 4; ++c)
                    if (ocol0 + 16 * c < OW) op[16 * c] = acc[c][r];
            }
        }
    }
}

extern "C" void kernel_launch(void* const* d_in, const int* in_sizes, int n_in,
                              void* d_out, int out_size, void* d_ws, size_t ws_size,
                              hipStream_t stream) {
    const float* X    = (const float*)d_in[0];
    const float* Wt   = (const float*)d_in[1];
    const float* bias = (const float*)d_in[2];
    float* out        = (float*)d_out;
    _Float16* Bp      = (_Float16*)d_ws;      // 11264 B

    build_B_kernel<<<dim3(22), dim3(256), 0, stream>>>(Wt, Bp);
    conv2d_dma2_kernel<<<dim3(NWG), dim3(256), 0, stream>>>(X, Bp, bias, out);
}

// Round 13
// 72.199 us; speedup vs baseline: 2.7123x; 1.0536x over previous
//
#include <hip/hip_runtime.h>

typedef _Float16 half8 __attribute__((ext_vector_type(8)));
typedef __fp16  fp16x2 __attribute__((ext_vector_type(2)));
typedef float f32x4 __attribute__((ext_vector_type(4)));

#define HH 6144
#define WW 6144
#define KH 11
#define KW 11
#define OH (HH - KH + 1)   // 6134
#define OW (WW - KW + 1)   // 6134

#define BROWS 32           // out rows per block
#define BCOLS 128          // out cols per block
#define SR 42              // staged input rows (32 + 10 halo)
#define SCH 36             // 16B fp32 chunks per row (144 f32; need 143)
#define ROWB 576           // F row bytes (36*16); H row (288 B) fits in place
#define A_TASKS 1512       // 42*36
#define A_PAD 1536         // 24 full DMA waves
#define B_SLOTS 448        // 440 real + 8 pad (16 B each)
#define B_BYTES 7168
#define TOT_WAVETASKS 31   // 24 A + 7 B
#define B_OFF 24576        // A_PAD*16
#define LDSB 31744         // B_OFF + B_BYTES
#define CV_TASKS 756       // 42 rows * 18 col-octs

#define TILES_X 48
#define TILES_Y 192
#define NWG (TILES_X * TILES_Y)   // 9216 = 8 * 1152

// ---- prep: compact B table ------------------------------------------------
// slot (kb*40+s), elem e: value W[kb][s+e-15] (zero outside [0,11))
// fragment for lane(n,h) at kb: slot s = 8h-n+15, elems e=0..7.
__global__ void build_B_kernel(const float* __restrict__ Wt,
                               _Float16* __restrict__ Bc) {
    const int t = (int)blockIdx.x * 256 + (int)threadIdx.x;
    if (t < B_SLOTS * 8) {
        const int e    = t & 7;
        const int slot = t >> 3;
        const int kb   = slot / 40;
        const int s    = slot - kb * 40;
        float v = 0.f;
        if (kb < KH) {
            const int d = s + e - 15;
            if (d >= 0 && d < KW) v = Wt[kb * KW + d];
        }
        Bc[t] = (_Float16)v;
    }
}

union pk2 { fp16x2 h; unsigned int u; };
static __device__ __forceinline__ unsigned int cvt2(float a, float b) {
#if defined(__has_builtin) && __has_builtin(__builtin_amdgcn_cvt_pkrtz)
    pk2 r; r.h = __builtin_amdgcn_cvt_pkrtz(a, b);
#else
    pk2 r; r.h[0] = (__fp16)a; r.h[1] = (__fp16)b;
#endif
    return r.u;
}

__global__ __launch_bounds__(256, 5)
void conv2d_dma3_kernel(const float* __restrict__ X,
                        const _Float16* __restrict__ Bc,
                        const float* __restrict__ bias,
                        float* __restrict__ out)
{
    __shared__ __align__(16) char lds[LDSB];

    // XCD-chunked remap (bijective: 9216 % 8 == 0)
    const int bid = (int)blockIdx.x;
    const int sb  = (bid & 7) * (NWG / 8) + (bid >> 3);
    const int txt = sb % TILES_X;
    const int tyt = sb / TILES_X;

    const int x0 = txt * BCOLS;
    const int y0 = tyt * BROWS;
    const int tid = (int)threadIdx.x;
    const int lane = tid & 63;
    const int wv = tid >> 6;
    const int n  = lane & 15;
    const int h  = lane >> 4;
    const int rt = wv & 1;          // row-tile (0,1)
    const int cs = wv >> 1;         // col strip of 64 (0,1)
    const float bv = bias[0];

    const bool interior = (txt < TILES_X - 1) && (tyt < TILES_Y - 1);

    // ---------------- stage: DMA global -> LDS, LINEAR layout ---------------
    if (interior) {
        #pragma unroll
        for (int k = 0; k < 8; ++k) {
            const int wabs = k * 4 + wv;              // wave-uniform
            if (wabs < TOT_WAVETASKS) {
                char* ldst = lds + wabs * 1024;       // uniform base; HW adds lane*16
                const void* src;
                if (wabs < 24) {
                    const int t = wabs * 64 + lane;
                    int r = t / SCH;
                    const int j = t - r * SCH;
                    if (r > SR - 1) r = SR - 1;       // pad tasks: benign clamp
                    src = (const void*)(X + (size_t)(y0 + r) * WW + (x0 + 4 * j));
                } else {
                    const int tb = (wabs - 24) * 64 + lane;
                    src = (const void*)((const char*)Bc + (size_t)tb * 16);
                }
                __builtin_amdgcn_global_load_lds(
                    (const __attribute__((address_space(1))) void*)src,
                    (__attribute__((address_space(3))) void*)ldst,
                    16, 0, 0);
            }
        }
    } else {
        #pragma unroll 1
        for (int k = 0; k < 8; ++k) {
            const int wabs = k * 4 + wv;
            if (wabs < TOT_WAVETASKS) {
                const int t = wabs * 64 + lane;
                if (wabs < 24) {
                    int r = t / SCH;
                    const int j = t - r * SCH;
                    if (r > SR - 1) r = SR - 1;
                    const int gy = y0 + r;
                    const int gx = x0 + 4 * j;
                    f32x4 v = {0.f, 0.f, 0.f, 0.f};
                    if (gy < HH) {
                        const float* rp = X + (size_t)gy * WW;
                        if (gx + 3 < WW) {
                            v = *reinterpret_cast<const f32x4*>(rp + gx);
                        } else {
                            if (gx + 0 < WW) v[0] = rp[gx + 0];
                            if (gx + 1 < WW) v[1] = rp[gx + 1];
                            if (gx + 2 < WW) v[2] = rp[gx + 2];
                        }
                    }
                    *reinterpret_cast<f32x4*>(lds + (size_t)t * 16) = v;
                } else {
                    const int tb = t - A_PAD;
                    *reinterpret_cast<uint4*>(lds + (size_t)t * 16) =
                        *reinterpret_cast<const uint4*>((const char*)Bc + (size_t)tb * 16);
                }
            }
        }
    }

    __syncthreads();   // drains all DMA (vmcnt(0)) once

    // ---------------- convert pass: fp32 F -> fp16 H, IN PLACE --------------
    // task idx: r = idx/18, m = idx%18 (col-oct). Read -> barrier -> write
    // H row r at r*576 + (r&7)*32 + m*16  (288+256 <= 576; rotation = banks).
    f32x4 CV[3][2];
    #pragma unroll
    for (int it = 0; it < 3; ++it) {
        const int idx = it * 256 + tid;
        if (idx < CV_TASKS) {
            const int r = idx / 18;
            const int m = idx - r * 18;
            const char* frow = lds + (size_t)(r * SCH + 2 * m) * 16;
            CV[it][0] = *reinterpret_cast<const f32x4*>(frow);
            CV[it][1] = *reinterpret_cast<const f32x4*>(frow + 16);
        }
    }

    __syncthreads();   // all F reads complete before any H write

    #pragma unroll
    for (int it = 0; it < 3; ++it) {
        const int idx = it * 256 + tid;
        if (idx < CV_TASKS) {
            const int r = idx / 18;
            const int m = idx - r * 18;
            union { unsigned int u[4]; uint4 q; } fr;
            fr.u[0] = cvt2(CV[it][0][0], CV[it][0][1]);
            fr.u[1] = cvt2(CV[it][0][2], CV[it][0][3]);
            fr.u[2] = cvt2(CV[it][1][0], CV[it][1][1]);
            fr.u[3] = cvt2(CV[it][1][2], CV[it][1][3]);
            *reinterpret_cast<uint4*>(
                lds + (size_t)r * ROWB + (r & 7) * 32 + m * 16) = fr.q;
        }
    }

    f32x4 acc[4];
    #pragma unroll
    for (int c = 0; c < 4; ++c) acc[c] = (f32x4){bv, bv, bv, bv};

    __syncthreads();

    // ---------------- compute: one b128 per MFMA (fp16) ---------------------
    // A(kb,c) lane(n,h): row r=16rt+n+kb, halves 64cs+16c+8h+[0,8)
    //   addr = r*576 + ((n+kb)&7)*32 + 128cs + 32c + 16h
    // B(kb) lane(n,h): slot 8h-n+15, addr = B_OFF + slot*16 + kb*640
    const char* abase = lds + (16 * rt + n) * ROWB + 128 * cs + 16 * h;
    const char* bbase = lds + B_OFF + (8 * h - n + 15) * 16;
    #pragma unroll
    for (int kb = 0; kb < 11; ++kb) {
        const half8 bf = *reinterpret_cast<const half8*>(bbase + kb * 640);
        const char* arow = abase + kb * ROWB + ((n + kb) & 7) * 32;
        #pragma unroll
        for (int c = 0; c < 4; ++c) {
            half8 a = *reinterpret_cast<const half8*>(arow + 32 * c);
            acc[c] = __builtin_amdgcn_mfma_f32_16x16x32_f16(a, bf, acc[c], 0, 0, 0);
        }
    }

    // ---------------- store: out row 16rt+4h+r, col 64cs+16c+n --------------
    const int orow0 = y0 + 16 * rt + 4 * h;
    const int ocol0 = x0 + 64 * cs + n;
    if (interior) {
        #pragma unroll
        for (int r = 0; r < 4; ++r) {
            float* op = out + (size_t)(orow0 + r) * OW + ocol0;
            #pragma unroll
            for (int c = 0; c < 4; ++c)
                op[16 * c] = acc[c][r];
        }
    } else {
        #pragma unroll
        for (int r = 0; r < 4; ++r) {
            if (orow0 + r < OH) {
                float* op = out + (size_t)(orow0 + r) * OW + ocol0;
                #pragma unroll
                for (int c = 0; c < 4; ++c)
                    if (ocol0 + 16 * c < OW) op[16 * c] = acc[c][r];
            }
        }
    }
}

extern "C" void kernel_launch(void* const* d_in, const int* in_sizes, int n_in,
                              void* d_out, int out_size, void* d_ws, size_t ws_size,
                              hipStream_t stream) {
    const float* X    = (const float*)d_in[0];
    const float* Wt   = (const float*)d_in[1];
    const float* bias = (const float*)d_in[2];
    float* out        = (float*)d_out;
    _Float16* Bc      = (_Float16*)d_ws;      // 7168 B

    build_B_kernel<<<dim3(14), dim3(256), 0, stream>>>(Wt, Bc);
    conv2d_dma3_kernel<<<dim3(NWG), dim3(256), 0, stream>>>(X, Bc, bias, out);
}